// Round 10
// baseline (188.743 us; speedup 1.0000x reference)
//
#include <hip/hip_runtime.h>
#include <math.h>

// SensorGNN: 2-layer GCN (N=50000, E=800000, F=128, H=64) + flat classifier (6 classes).
// Graph build = counting sort by dst-range + per-node src-half split:
//   hist_ranges -> scan_ghist -> scatter_ranges -> csr_range (dinv/offs/splits/srt).
// Aggregation is 2-pass: pass0 gathers src<NHALF (3.2MB bf16 G slab, L2-resident on every
// XCD) + self loop -> raw sums in H; pass1 gathers src>=NHALF + H -> dinv/bias/relu.
// Round-3: same-line global atomics serialize cross-XCD -> two-stage reduce.
// Round-4/5: random global atomic scatter bounces lines via HBM; ILP can't fix.
// Round-6: range partition w/ edge replication = 11% occupancy regression.
// Round-7/8: all aggregate ILP structures ~57us -> random-gather service limit, not chain.
// Round-9: bf16 G (halved bytes) only -21% -> latency/service-bound vs >4MB working set.
//   Fix: src-half partitioning so each pass's gather slab (3.2MB) fits every XCD's L2.

#define NCH 256          // edge chunk blocks
#define RBITS 10         // range = 1024 nodes
#define NR_MAX 64

__device__ __forceinline__ ushort f32_to_bf16(float f) {  // RTN-even
  unsigned u = __float_as_uint(f);
  return (ushort)((u + 0x7fffu + ((u >> 16) & 1u)) >> 16);
}
__device__ __forceinline__ float bf16_to_f32(ushort h) {
  return __uint_as_float(((unsigned)h) << 16);
}

// ---------------- pass A: per-chunk range histograms ----------------

__global__ __launch_bounds__(256) void hist_ranges(
    const int* __restrict__ dst, int* __restrict__ ghist, int NR, int E) {
  __shared__ int h[NR_MAX];
  int tid = threadIdx.x, c = blockIdx.x;
  if (tid < NR) h[tid] = 0;
  __syncthreads();
  int E4 = E >> 2;
  int CH4 = (E4 + NCH - 1) / NCH;
  int i0 = c * CH4, i1 = min(i0 + CH4, E4);
  const int4* d4 = (const int4*)dst;
  for (int i = i0 + tid; i < i1; i += 256) {
    int4 d = d4[i];
    atomicAdd(&h[d.x >> RBITS], 1);
    atomicAdd(&h[d.y >> RBITS], 1);
    atomicAdd(&h[d.z >> RBITS], 1);
    atomicAdd(&h[d.w >> RBITS], 1);
  }
  if (c == NCH - 1) {
    for (int e = (E4 << 2) + tid; e < E; e += 256) atomicAdd(&h[dst[e] >> RBITS], 1);
  }
  __syncthreads();
  if (tid < NR) ghist[tid * NCH + c] = h[tid];  // range-major, chunk-minor
}

// ---------------- pass B: exclusive scan of ghist[NR*NCH] (single block) ----------------

__global__ __launch_bounds__(1024) void scan_ghist(int* __restrict__ g, int M) {
  __shared__ int wtot[16];
  int tid = threadIdx.x, lane = tid & 63, wv = tid >> 6;
  int SEG = (M + 1023) >> 10;
  int base = tid * SEG;
  int s = 0;
  for (int k = 0; k < SEG; ++k) { int i = base + k; if (i < M) s += g[i]; }
  int x = s;
#pragma unroll
  for (int d = 1; d < 64; d <<= 1) { int y = __shfl_up(x, d, 64); if (lane >= d) x += y; }
  if (lane == 63) wtot[wv] = x;
  __syncthreads();
  if (wv == 0 && lane < 16) {
    int t = wtot[lane], xx = t;
#pragma unroll
    for (int d = 1; d < 16; d <<= 1) { int y = __shfl_up(xx, d, 64); if (lane >= d) xx += y; }
    wtot[lane] = xx - t;  // exclusive
  }
  __syncthreads();
  int run = x - s + wtot[wv];
  for (int k = 0; k < SEG; ++k) {
    int i = base + k;
    if (i < M) { int tmp = g[i]; g[i] = run; run += tmp; }
  }
}

// ---------------- pass C: scatter (src,dst) pairs into range-sorted ebuf ----------------

__global__ __launch_bounds__(256) void scatter_ranges(
    const int* __restrict__ src, const int* __restrict__ dst,
    const int* __restrict__ ghist, int2* __restrict__ ebuf, int NR, int E) {
  __shared__ int cur[NR_MAX];
  int tid = threadIdx.x, c = blockIdx.x;
  if (tid < NR) cur[tid] = ghist[tid * NCH + c];
  __syncthreads();
  int E4 = E >> 2;
  int CH4 = (E4 + NCH - 1) / NCH;
  int i0 = c * CH4, i1 = min(i0 + CH4, E4);
  const int4* d4 = (const int4*)dst;
  const int4* s4 = (const int4*)src;
  for (int i = i0 + tid; i < i1; i += 256) {
    int4 d = d4[i];
    int4 s = s4[i];
    ebuf[atomicAdd(&cur[d.x >> RBITS], 1)] = make_int2(s.x, d.x);
    ebuf[atomicAdd(&cur[d.y >> RBITS], 1)] = make_int2(s.y, d.y);
    ebuf[atomicAdd(&cur[d.z >> RBITS], 1)] = make_int2(s.z, d.z);
    ebuf[atomicAdd(&cur[d.w >> RBITS], 1)] = make_int2(s.w, d.w);
  }
  if (c == NCH - 1) {
    for (int e = (E4 << 2) + tid; e < E; e += 256)
      ebuf[atomicAdd(&cur[dst[e] >> RBITS], 1)] = make_int2(src[e], dst[e]);
  }
}

// ---------------- pass D: per-range CSR build with src-half split ----------------
// srt layout per node: [offs[n], splits[n]) = src<NHALF, [splits[n], offs[n+1]) = rest.

__global__ __launch_bounds__(1024) void csr_range(
    const int2* __restrict__ ebuf, const int* __restrict__ ghist,
    int* __restrict__ offs, int* __restrict__ splits, int* __restrict__ srt,
    float* __restrict__ dinv, int N, int E, int NR, int NHALF) {
  __shared__ int hT[1024];  // total counts -> low cursor
  __shared__ int hL[1024];  // low-half counts -> high cursor
  __shared__ int wtot[16];
  int r = blockIdx.x;
  int lo = r << RBITS;
  int len = min(1024, N - lo);
  int tid = threadIdx.x, lane = tid & 63, wv = tid >> 6;
  int S  = ghist[r * NCH];
  int S1 = (r + 1 < NR) ? ghist[(r + 1) * NCH] : E;
  if (tid < len) { hT[tid] = 0; hL[tid] = 0; }
  __syncthreads();
  for (int i = S + tid; i < S1; i += 1024) {
    int2 e = ebuf[i];
    atomicAdd(&hT[e.y - lo], 1);
    if (e.x < NHALF) atomicAdd(&hL[e.y - lo], 1);
  }
  __syncthreads();
  int v = (tid < len) ? hT[tid] : 0;
  if (tid < len) dinv[lo + tid] = rsqrtf((float)(v + 1));  // +1 self loop
  // exclusive scan of v across 1024 threads
  int x = v;
#pragma unroll
  for (int d = 1; d < 64; d <<= 1) { int y = __shfl_up(x, d, 64); if (lane >= d) x += y; }
  if (lane == 63) wtot[wv] = x;
  __syncthreads();
  if (wv == 0 && lane < 16) {
    int t = wtot[lane], xx = t;
#pragma unroll
    for (int d = 1; d < 16; d <<= 1) { int y = __shfl_up(xx, d, 64); if (lane >= d) xx += y; }
    wtot[lane] = xx - t;
  }
  __syncthreads();
  int excl = x - v + wtot[wv];
  if (tid < len) {
    int base = S + excl;
    int sp = base + hL[tid];   // own-thread read before overwrite
    offs[lo + tid] = base;
    splits[lo + tid] = sp;
    hT[tid] = base;            // low-half cursor
    hL[tid] = sp;              // high-half cursor
  }
  if (r == 0 && tid == 0) offs[N] = E;
  __syncthreads();
  for (int i = S + tid; i < S1; i += 1024) {
    int2 e = ebuf[i];
    int idx = e.y - lo;
    int p = (e.x < NHALF) ? atomicAdd(&hT[idx], 1) : atomicAdd(&hL[idx], 1);
    srt[p] = e.x;
  }
}

// ---------------- dense transform: Gb = bf16((X @ W) * dinv[row]) ----------------
// block = 256 (4 waves), 32 rows/block, each wave computes 8 rows x 64 cols.
// Unroll capped at 4 to avoid the round-1 VGPR blowup (256 VGPR + 380MB scratch spill).

template <int K, int ROWS>
__global__ __launch_bounds__(256) void gemm_scale(
    const float* __restrict__ X, const float* __restrict__ W,
    const float* __restrict__ dinv, ushort* __restrict__ Gb, int N) {
  __shared__ float smw[K * 64];
  __shared__ float xs[ROWS * K];
  int tid = threadIdx.x, lane = tid & 63, wv = tid >> 6;
  for (int idx = tid; idx < K * 16; idx += 256)
    ((float4*)smw)[idx] = ((const float4*)W)[idx];
  int row0 = blockIdx.x * ROWS;
  int base = row0 * K;
  int cnt4 = (min(ROWS * K, N * K - base)) >> 2;  // K%4==0 so exact
  const float4* X4 = (const float4*)(X + base);
  for (int idx = tid; idx < cnt4; idx += 256) ((float4*)xs)[idx] = X4[idx];
  __syncthreads();

  constexpr int RW = ROWS / 4;  // rows per wave
  float acc[RW];
#pragma unroll
  for (int r = 0; r < RW; ++r) acc[r] = 0.f;
  const float* xr = &xs[(wv * RW) * K];
#pragma unroll 4
  for (int k = 0; k < K; ++k) {
    float wval = smw[k * 64 + lane];  // lane-contiguous: 2-way bank alias = free
#pragma unroll
    for (int r = 0; r < RW; ++r) acc[r] = fmaf(xr[r * K + k], wval, acc[r]);  // LDS broadcast
  }
#pragma unroll
  for (int r = 0; r < RW; ++r) {
    int row = row0 + wv * RW + r;
    if (row < N) Gb[(size_t)row * 64 + lane] = f32_to_bf16(acc[r] * dinv[row]);
  }
}

// ---------------- 2-pass aggregation ----------------
// PASS 0: acc = G[node] (self, sequential) + sum of src<NHALF rows (L2-hot 3.2MB slab);
//         store raw float4 sums to H.
// PASS 1: acc = H[node] + sum of src>=NHALF rows; H = relu(acc*dinv + bias).
// one wave per node; lane = sub*16 + fl; indices hoisted to regs + dynamic shfl;
// 8 rows in flight.

template <int PASS>
__global__ __launch_bounds__(256) void aggregate(
    const ushort* __restrict__ Gb, const int* __restrict__ offs,
    const int* __restrict__ splits, const int* __restrict__ srt,
    const float* __restrict__ dinv, const float* __restrict__ bias,
    float* __restrict__ H, int N) {
  int lane = threadIdx.x & 63, wv = threadIdx.x >> 6;
  int sub = lane >> 4, fl = lane & 15;
  int node = blockIdx.x * 4 + wv;
  if (node >= N) return;
  const ushort4* G2 = (const ushort4*)Gb;  // 16 x ushort4 per 64-feat row

  int e0, e1;
  if (PASS == 0) { e0 = offs[node]; e1 = splits[node]; }
  else           { e0 = splits[node]; e1 = offs[node + 1]; }
  int deg = e1 - e0;

  float4 accA = make_float4(0.f, 0.f, 0.f, 0.f);
  float4 accB = make_float4(0.f, 0.f, 0.f, 0.f);
  if (sub == 0) {
    if (PASS == 0) {  // self loop (sequential row read)
      ushort4 q = G2[(size_t)node * 16 + fl];
      accA.x = bf16_to_f32(q.x); accA.y = bf16_to_f32(q.y);
      accA.z = bf16_to_f32(q.z); accA.w = bf16_to_f32(q.w);
    } else {          // carry raw sums from pass 0
      accA = ((const float4*)H)[(size_t)node * 16 + fl];
    }
  }

  // hoist up to 64 edge indices into registers (coalesced)
  int pre = (deg > 0) ? srt[e0 + min(lane, deg - 1)] : 0;

  int dcap = min(deg, 64);
  int base = 0;
  for (; base + 7 < dcap; base += 8) {   // 8 rows in flight, no index-load chain
    int sA = __shfl(pre, base + sub, 64);
    int sB = __shfl(pre, base + 4 + sub, 64);
    ushort4 qA = G2[(size_t)sA * 16 + fl];
    ushort4 qB = G2[(size_t)sB * 16 + fl];
    accA.x += bf16_to_f32(qA.x); accA.y += bf16_to_f32(qA.y);
    accA.z += bf16_to_f32(qA.z); accA.w += bf16_to_f32(qA.w);
    accB.x += bf16_to_f32(qB.x); accB.y += bf16_to_f32(qB.y);
    accB.z += bf16_to_f32(qB.z); accB.w += bf16_to_f32(qB.w);
  }
  for (; base + 3 < dcap; base += 4) {
    int s = __shfl(pre, base + sub, 64);
    ushort4 q = G2[(size_t)s * 16 + fl];
    accA.x += bf16_to_f32(q.x); accA.y += bf16_to_f32(q.y);
    accA.z += bf16_to_f32(q.z); accA.w += bf16_to_f32(q.w);
  }
  int e = e0 + base;
  for (; e + 3 < e1; e += 4) {           // deg>64 spillover (rare)
    int s = srt[e + sub];
    ushort4 q = G2[(size_t)s * 16 + fl];
    accA.x += bf16_to_f32(q.x); accA.y += bf16_to_f32(q.y);
    accA.z += bf16_to_f32(q.z); accA.w += bf16_to_f32(q.w);
  }
  int rem = e1 - e;                      // 0..3 remainder
  if (sub < rem) {
    int s = srt[e + sub];
    ushort4 q = G2[(size_t)s * 16 + fl];
    accA.x += bf16_to_f32(q.x); accA.y += bf16_to_f32(q.y);
    accA.z += bf16_to_f32(q.z); accA.w += bf16_to_f32(q.w);
  }

  float4 acc;
  acc.x = accA.x + accB.x; acc.y = accA.y + accB.y;
  acc.z = accA.z + accB.z; acc.w = accA.w + accB.w;
#pragma unroll
  for (int m = 16; m < 64; m <<= 1) {
    acc.x += __shfl_xor(acc.x, m, 64);
    acc.y += __shfl_xor(acc.y, m, 64);
    acc.z += __shfl_xor(acc.z, m, 64);
    acc.w += __shfl_xor(acc.w, m, 64);
  }
  if (sub == 0) {
    if (PASS == 0) {
      ((float4*)H)[(size_t)node * 16 + fl] = acc;  // raw partial sums
    } else {
      float dn = dinv[node];
      float4 bb = ((const float4*)bias)[fl];
      float4 r;
      r.x = fmaxf(fmaf(acc.x, dn, bb.x), 0.f);
      r.y = fmaxf(fmaf(acc.y, dn, bb.y), 0.f);
      r.z = fmaxf(fmaf(acc.z, dn, bb.z), 0.f);
      r.w = fmaxf(fmaf(acc.w, dn, bb.w), 0.f);
      ((float4*)H)[(size_t)node * 16 + fl] = r;
    }
  }
}

// ---------------- classifier: part[b][c] = block-partial of sum_i H[i]*Wc[i*6+c] --------
// LCM(4,6)=12: each thread owns 12 consecutive Wc floats (2 rows, 3x float4) + float2 of H.
// NO atomics: per-block partials, reduced by reduce_softmax (round-3: atomic tail was 160us).

__global__ __launch_bounds__(256) void classifier(
    const float* __restrict__ H, const float* __restrict__ Wc,
    float* __restrict__ part, int M12) {
  float a[6] = {0.f, 0.f, 0.f, 0.f, 0.f, 0.f};
  int stride = gridDim.x * blockDim.x;
  for (int g = blockIdx.x * blockDim.x + threadIdx.x; g < M12; g += stride) {
    const float4* w4 = (const float4*)Wc + (size_t)g * 3;
    float4 v0 = w4[0];
    float4 v1 = w4[1];
    float4 v2 = w4[2];
    float2 h = ((const float2*)H)[g];
    a[0] = fmaf(h.x, v0.x, a[0]); a[1] = fmaf(h.x, v0.y, a[1]);
    a[2] = fmaf(h.x, v0.z, a[2]); a[3] = fmaf(h.x, v0.w, a[3]);
    a[4] = fmaf(h.x, v1.x, a[4]); a[5] = fmaf(h.x, v1.y, a[5]);
    a[0] = fmaf(h.y, v1.z, a[0]); a[1] = fmaf(h.y, v1.w, a[1]);
    a[2] = fmaf(h.y, v2.x, a[2]); a[3] = fmaf(h.y, v2.y, a[3]);
    a[4] = fmaf(h.y, v2.z, a[4]); a[5] = fmaf(h.y, v2.w, a[5]);
  }
#pragma unroll
  for (int c = 0; c < 6; ++c) {
    for (int d = 32; d > 0; d >>= 1) a[c] += __shfl_down(a[c], d, 64);
  }
  __shared__ float sh[4][6];
  int lane = threadIdx.x & 63, wv = threadIdx.x >> 6;
  if (lane == 0) {
#pragma unroll
    for (int c = 0; c < 6; ++c) sh[wv][c] = a[c];
  }
  __syncthreads();
  if (threadIdx.x == 0) {
#pragma unroll
    for (int c = 0; c < 6; ++c)
      part[(size_t)blockIdx.x * 6 + c] = sh[0][c] + sh[1][c] + sh[2][c] + sh[3][c];
  }
}

// single block: sum part[nb][6], add bias, softmax, write out[6]
__global__ __launch_bounds__(256) void reduce_softmax(
    const float* __restrict__ part, int nb,
    const float* __restrict__ bc, float* __restrict__ out) {
  int tid = threadIdx.x, lane = tid & 63, wv = tid >> 6;
  float a[6] = {0.f, 0.f, 0.f, 0.f, 0.f, 0.f};
  for (int b = tid; b < nb; b += 256) {
    const float* p = part + (size_t)b * 6;
#pragma unroll
    for (int c = 0; c < 6; ++c) a[c] += p[c];
  }
#pragma unroll
  for (int c = 0; c < 6; ++c) {
    for (int d = 32; d > 0; d >>= 1) a[c] += __shfl_down(a[c], d, 64);
  }
  __shared__ float sh[4][6];
  if (lane == 0) {
#pragma unroll
    for (int c = 0; c < 6; ++c) sh[wv][c] = a[c];
  }
  __syncthreads();
  if (tid == 0) {
    float l[6], m = -1e30f;
#pragma unroll
    for (int c = 0; c < 6; ++c) {
      l[c] = sh[0][c] + sh[1][c] + sh[2][c] + sh[3][c] + bc[c];
      m = fmaxf(m, l[c]);
    }
    float s = 0.f;
#pragma unroll
    for (int c = 0; c < 6; ++c) { l[c] = __expf(l[c] - m); s += l[c]; }
    float inv = 1.f / s;
#pragma unroll
    for (int c = 0; c < 6; ++c) out[c] = l[c] * inv;
  }
}

// ---------------- launch ----------------

static inline size_t align4up(size_t x) { return (x + 3) & ~(size_t)3; }  // 4-elem = 16B

extern "C" void kernel_launch(void* const* d_in, const int* in_sizes, int n_in,
                              void* d_out, int out_size, void* d_ws, size_t ws_size,
                              hipStream_t stream) {
  const float* x  = (const float*)d_in[0];
  const int*   ei = (const int*)d_in[1];
  const float* W1 = (const float*)d_in[2];
  const float* b1 = (const float*)d_in[3];
  const float* W2 = (const float*)d_in[4];
  const float* b2 = (const float*)d_in[5];
  const float* Wc = (const float*)d_in[6];
  const float* bc = (const float*)d_in[7];
  float* out = (float*)d_out;

  const int N = in_sizes[0] / 128;  // 50000
  const int E = in_sizes[1] / 2;    // 800000
  const int* esrc = ei;
  const int* edst = ei + E;
  const int NR = (N + 1023) >> RBITS;  // 49 ranges (<= NR_MAX)
  const int CGRID = 2048;              // classifier blocks
  const int NHALF = (N / 2 + 3) & ~3;  // 25000: src-half split point

  // 16B-aligned workspace carve
  size_t o = 0;
  int* offs   = (int*)d_ws + o;           o = align4up(o + N + 1);
  int* splits = (int*)d_ws + o;           o = align4up(o + N);
  int* srt    = (int*)d_ws + o;           o = align4up(o + E);
  float* dinv = (float*)d_ws + o;         o = align4up(o + N);
  int* ghist  = (int*)d_ws + o;           o = align4up(o + (size_t)NR * NCH);
  ushort* Gb  = (ushort*)((int*)d_ws + o); o = align4up(o + (size_t)N * 32);  // N*64 bf16
  float* bufB = (float*)d_ws + o;         o = align4up(o + (size_t)N * 64);
  float* part = (float*)d_ws + o;         o = align4up(o + (size_t)CGRID * 6);
  int2* ebuf  = (int2*)bufB;  // aliases bufB: dead after csr_range, bufB written by agg pass0

  hist_ranges<<<NCH, 256, 0, stream>>>(edst, ghist, NR, E);
  scan_ghist<<<1, 1024, 0, stream>>>(ghist, NR * NCH);
  scatter_ranges<<<NCH, 256, 0, stream>>>(esrc, edst, ghist, ebuf, NR, E);
  csr_range<<<NR, 1024, 0, stream>>>(ebuf, ghist, offs, splits, srt, dinv, N, E, NR, NHALF);

  const int AGRID = (N + 3) / 4;
  gemm_scale<128, 32><<<(N + 31) / 32, 256, 0, stream>>>(x, W1, dinv, Gb, N);
  aggregate<0><<<AGRID, 256, 0, stream>>>(Gb, offs, splits, srt, dinv, b1, bufB, N);
  aggregate<1><<<AGRID, 256, 0, stream>>>(Gb, offs, splits, srt, dinv, b1, bufB, N);
  gemm_scale<64, 32><<<(N + 31) / 32, 256, 0, stream>>>(bufB, W2, dinv, Gb, N);
  aggregate<0><<<AGRID, 256, 0, stream>>>(Gb, offs, splits, srt, dinv, b2, bufB, N);
  aggregate<1><<<AGRID, 256, 0, stream>>>(Gb, offs, splits, srt, dinv, b2, bufB, N);

  // M12 = (N*64*6)/12 = N*32 groups of 12 Wc floats
  classifier<<<CGRID, 256, 0, stream>>>(bufB, Wc, part, N * 32);
  reduce_softmax<<<1, 256, 0, stream>>>(part, CGRID, bc, out);
}

// Round 11
// 164.251 us; speedup vs baseline: 1.1491x; 1.1491x over previous
//
#include <hip/hip_runtime.h>
#include <math.h>

// SensorGNN: 2-layer GCN (N=50000, E=800000, F=128, H=64) + flat classifier (6 classes).
// Graph build = counting sort by dst-range: hist_ranges -> scan_ghist -> scatter_ranges ->
//   csr_range (dinv/offs/srt). Then gemm1 -> agg1 -> gemm2 -> agg2(+fused classifier) ->
//   reduce+softmax.
// Round-3: same-line global atomics serialize cross-XCD -> two-stage reduce.
// Round-4/5: random global atomic scatter bounces lines via HBM; ILP can't fix.
// Round-6: range partition w/ edge replication = 11% occupancy regression.
// Round-7/8: all aggregate ILP structures ~57us -> random-gather service limit, not chain.
// Round-9: bf16 G halved lines -> only -21% => MLP(MSHR)-latency bound, not BW.
// Round-10: 2-pass L2-residency split = +23us (H round-trip + no gather win) -> REVERTED.
// Round-11: gather is at its MLP floor; exploit its idle BW/VALU: classifier fused into
//   agg2 epilogue (h never materialized, Wc stream hides under gather latency).

#define NCH 256          // edge chunk blocks
#define RBITS 10         // range = 1024 nodes
#define NR_MAX 64

__device__ __forceinline__ ushort f32_to_bf16(float f) {  // RTN-even
  unsigned u = __float_as_uint(f);
  return (ushort)((u + 0x7fffu + ((u >> 16) & 1u)) >> 16);
}
__device__ __forceinline__ float bf16_to_f32(ushort h) {
  return __uint_as_float(((unsigned)h) << 16);
}

// ---------------- pass A: per-chunk range histograms ----------------

__global__ __launch_bounds__(256) void hist_ranges(
    const int* __restrict__ dst, int* __restrict__ ghist, int NR, int E) {
  __shared__ int h[NR_MAX];
  int tid = threadIdx.x, c = blockIdx.x;
  if (tid < NR) h[tid] = 0;
  __syncthreads();
  int E4 = E >> 2;
  int CH4 = (E4 + NCH - 1) / NCH;
  int i0 = c * CH4, i1 = min(i0 + CH4, E4);
  const int4* d4 = (const int4*)dst;
  for (int i = i0 + tid; i < i1; i += 256) {
    int4 d = d4[i];
    atomicAdd(&h[d.x >> RBITS], 1);
    atomicAdd(&h[d.y >> RBITS], 1);
    atomicAdd(&h[d.z >> RBITS], 1);
    atomicAdd(&h[d.w >> RBITS], 1);
  }
  if (c == NCH - 1) {
    for (int e = (E4 << 2) + tid; e < E; e += 256) atomicAdd(&h[dst[e] >> RBITS], 1);
  }
  __syncthreads();
  if (tid < NR) ghist[tid * NCH + c] = h[tid];  // range-major, chunk-minor
}

// ---------------- pass B: exclusive scan of ghist[NR*NCH] (single block) ----------------

__global__ __launch_bounds__(1024) void scan_ghist(int* __restrict__ g, int M) {
  __shared__ int wtot[16];
  int tid = threadIdx.x, lane = tid & 63, wv = tid >> 6;
  int SEG = (M + 1023) >> 10;
  int base = tid * SEG;
  int s = 0;
  for (int k = 0; k < SEG; ++k) { int i = base + k; if (i < M) s += g[i]; }
  int x = s;
#pragma unroll
  for (int d = 1; d < 64; d <<= 1) { int y = __shfl_up(x, d, 64); if (lane >= d) x += y; }
  if (lane == 63) wtot[wv] = x;
  __syncthreads();
  if (wv == 0 && lane < 16) {
    int t = wtot[lane], xx = t;
#pragma unroll
    for (int d = 1; d < 16; d <<= 1) { int y = __shfl_up(xx, d, 64); if (lane >= d) xx += y; }
    wtot[lane] = xx - t;  // exclusive
  }
  __syncthreads();
  int run = x - s + wtot[wv];
  for (int k = 0; k < SEG; ++k) {
    int i = base + k;
    if (i < M) { int tmp = g[i]; g[i] = run; run += tmp; }
  }
}

// ---------------- pass C: scatter (src,dst) pairs into range-sorted ebuf ----------------

__global__ __launch_bounds__(256) void scatter_ranges(
    const int* __restrict__ src, const int* __restrict__ dst,
    const int* __restrict__ ghist, int2* __restrict__ ebuf, int NR, int E) {
  __shared__ int cur[NR_MAX];
  int tid = threadIdx.x, c = blockIdx.x;
  if (tid < NR) cur[tid] = ghist[tid * NCH + c];
  __syncthreads();
  int E4 = E >> 2;
  int CH4 = (E4 + NCH - 1) / NCH;
  int i0 = c * CH4, i1 = min(i0 + CH4, E4);
  const int4* d4 = (const int4*)dst;
  const int4* s4 = (const int4*)src;
  for (int i = i0 + tid; i < i1; i += 256) {
    int4 d = d4[i];
    int4 s = s4[i];
    ebuf[atomicAdd(&cur[d.x >> RBITS], 1)] = make_int2(s.x, d.x);
    ebuf[atomicAdd(&cur[d.y >> RBITS], 1)] = make_int2(s.y, d.y);
    ebuf[atomicAdd(&cur[d.z >> RBITS], 1)] = make_int2(s.z, d.z);
    ebuf[atomicAdd(&cur[d.w >> RBITS], 1)] = make_int2(s.w, d.w);
  }
  if (c == NCH - 1) {
    for (int e = (E4 << 2) + tid; e < E; e += 256)
      ebuf[atomicAdd(&cur[dst[e] >> RBITS], 1)] = make_int2(src[e], dst[e]);
  }
}

// ---------------- pass D: per-range CSR build (dinv, offs, srt) ----------------

__global__ __launch_bounds__(1024) void csr_range(
    const int2* __restrict__ ebuf, const int* __restrict__ ghist,
    int* __restrict__ offs, int* __restrict__ srt, float* __restrict__ dinv,
    int N, int E, int NR) {
  __shared__ int hist[1024];
  __shared__ int wtot[16];
  int r = blockIdx.x;
  int lo = r << RBITS;
  int len = min(1024, N - lo);
  int tid = threadIdx.x, lane = tid & 63, wv = tid >> 6;
  int S  = ghist[r * NCH];
  int S1 = (r + 1 < NR) ? ghist[(r + 1) * NCH] : E;
  if (tid < len) hist[tid] = 0;
  __syncthreads();
  for (int i = S + tid; i < S1; i += 1024) atomicAdd(&hist[ebuf[i].y - lo], 1);
  __syncthreads();
  int v = (tid < len) ? hist[tid] : 0;
  if (tid < len) dinv[lo + tid] = rsqrtf((float)(v + 1));  // +1 self loop
  // exclusive scan of v across 1024 threads
  int x = v;
#pragma unroll
  for (int d = 1; d < 64; d <<= 1) { int y = __shfl_up(x, d, 64); if (lane >= d) x += y; }
  if (lane == 63) wtot[wv] = x;
  __syncthreads();
  if (wv == 0 && lane < 16) {
    int t = wtot[lane], xx = t;
#pragma unroll
    for (int d = 1; d < 16; d <<= 1) { int y = __shfl_up(xx, d, 64); if (lane >= d) xx += y; }
    wtot[lane] = xx - t;
  }
  __syncthreads();
  int excl = x - v + wtot[wv];
  if (tid < len) {
    offs[lo + tid] = S + excl;
    hist[tid] = S + excl;  // reuse as cursor
  }
  if (r == 0 && tid == 0) offs[N] = E;
  __syncthreads();
  for (int i = S + tid; i < S1; i += 1024) {
    int2 e = ebuf[i];
    srt[atomicAdd(&hist[e.y - lo], 1)] = e.x;
  }
}

// ---------------- dense transform: Gb = bf16((X @ W) * dinv[row]) ----------------
// block = 256 (4 waves), 32 rows/block, each wave computes 8 rows x 64 cols.
// Unroll capped at 4 to avoid the round-1 VGPR blowup (256 VGPR + 380MB scratch spill).

template <int K, int ROWS>
__global__ __launch_bounds__(256) void gemm_scale(
    const float* __restrict__ X, const float* __restrict__ W,
    const float* __restrict__ dinv, ushort* __restrict__ Gb, int N) {
  __shared__ float smw[K * 64];
  __shared__ float xs[ROWS * K];
  int tid = threadIdx.x, lane = tid & 63, wv = tid >> 6;
  for (int idx = tid; idx < K * 16; idx += 256)
    ((float4*)smw)[idx] = ((const float4*)W)[idx];
  int row0 = blockIdx.x * ROWS;
  int base = row0 * K;
  int cnt4 = (min(ROWS * K, N * K - base)) >> 2;  // K%4==0 so exact
  const float4* X4 = (const float4*)(X + base);
  for (int idx = tid; idx < cnt4; idx += 256) ((float4*)xs)[idx] = X4[idx];
  __syncthreads();

  constexpr int RW = ROWS / 4;  // rows per wave
  float acc[RW];
#pragma unroll
  for (int r = 0; r < RW; ++r) acc[r] = 0.f;
  const float* xr = &xs[(wv * RW) * K];
#pragma unroll 4
  for (int k = 0; k < K; ++k) {
    float wval = smw[k * 64 + lane];  // lane-contiguous: 2-way bank alias = free
#pragma unroll
    for (int r = 0; r < RW; ++r) acc[r] = fmaf(xr[r * K + k], wval, acc[r]);  // LDS broadcast
  }
#pragma unroll
  for (int r = 0; r < RW; ++r) {
    int row = row0 + wv * RW + r;
    if (row < N) Gb[(size_t)row * 64 + lane] = f32_to_bf16(acc[r] * dinv[row]);
  }
}

// ---------------- aggregation (+ optional fused classifier) ----------------
// one wave per node; lane = sub*16 + fl; indices hoisted to regs + dynamic shfl;
// 8 bf16 rows (2 lines each) in flight. After the butterfly reduce ALL lanes hold the
// full sum for their feature quad.
// CLS=0: H[node] = relu(acc*dinv + bias)  (layer-1 output, feeds gemm2).
// CLS=1: h is never stored; sub-0 lanes dot relu'd quad with node's Wc slice
//        (24 contiguous floats/lane, coalesced) -> block partial part[blk][6].

template <int CLS>
__global__ __launch_bounds__(256) void aggregate(
    const ushort* __restrict__ Gb, const int* __restrict__ offs,
    const int* __restrict__ srt, const float* __restrict__ dinv,
    const float* __restrict__ bias, const float* __restrict__ Wc,
    float* __restrict__ H, float* __restrict__ part, int N) {
  int lane = threadIdx.x & 63, wv = threadIdx.x >> 6;
  int sub = lane >> 4, fl = lane & 15;
  int node = blockIdx.x * 4 + wv;
  const ushort4* G2 = (const ushort4*)Gb;  // 16 x ushort4 per 64-feat row

  if (CLS == 0 && node >= N) return;  // CLS=1 must not early-return (block reduce below)

  int e0 = 0, e1 = 0;
  if (node < N) { e0 = offs[node]; e1 = offs[node + 1]; }
  int deg = e1 - e0;

  float4 accA = make_float4(0.f, 0.f, 0.f, 0.f);
  float4 accB = make_float4(0.f, 0.f, 0.f, 0.f);
  if (sub == 0 && node < N) {  // self loop
    ushort4 q = G2[(size_t)node * 16 + fl];
    accA.x = bf16_to_f32(q.x); accA.y = bf16_to_f32(q.y);
    accA.z = bf16_to_f32(q.z); accA.w = bf16_to_f32(q.w);
  }

  // hoist up to 64 edge indices into registers (coalesced; mean deg 16)
  int pre = (deg > 0) ? srt[e0 + min(lane, deg - 1)] : 0;

  int dcap = min(deg, 64);
  int base = 0;
  for (; base + 7 < dcap; base += 8) {   // 8 rows in flight, no index-load chain
    int sA = __shfl(pre, base + sub, 64);
    int sB = __shfl(pre, base + 4 + sub, 64);
    ushort4 qA = G2[(size_t)sA * 16 + fl];
    ushort4 qB = G2[(size_t)sB * 16 + fl];
    accA.x += bf16_to_f32(qA.x); accA.y += bf16_to_f32(qA.y);
    accA.z += bf16_to_f32(qA.z); accA.w += bf16_to_f32(qA.w);
    accB.x += bf16_to_f32(qB.x); accB.y += bf16_to_f32(qB.y);
    accB.z += bf16_to_f32(qB.z); accB.w += bf16_to_f32(qB.w);
  }
  for (; base + 3 < dcap; base += 4) {
    int s = __shfl(pre, base + sub, 64);
    ushort4 q = G2[(size_t)s * 16 + fl];
    accA.x += bf16_to_f32(q.x); accA.y += bf16_to_f32(q.y);
    accA.z += bf16_to_f32(q.z); accA.w += bf16_to_f32(q.w);
  }
  int e = e0 + base;
  for (; e + 3 < e1; e += 4) {           // deg>64 spillover (rare)
    int s = srt[e + sub];
    ushort4 q = G2[(size_t)s * 16 + fl];
    accA.x += bf16_to_f32(q.x); accA.y += bf16_to_f32(q.y);
    accA.z += bf16_to_f32(q.z); accA.w += bf16_to_f32(q.w);
  }
  int rem = e1 - e;                      // 0..3 remainder
  if (sub < rem) {
    int s = srt[e + sub];
    ushort4 q = G2[(size_t)s * 16 + fl];
    accA.x += bf16_to_f32(q.x); accA.y += bf16_to_f32(q.y);
    accA.z += bf16_to_f32(q.z); accA.w += bf16_to_f32(q.w);
  }

  float4 acc;
  acc.x = accA.x + accB.x; acc.y = accA.y + accB.y;
  acc.z = accA.z + accB.z; acc.w = accA.w + accB.w;
#pragma unroll
  for (int m = 16; m < 64; m <<= 1) {
    acc.x += __shfl_xor(acc.x, m, 64);
    acc.y += __shfl_xor(acc.y, m, 64);
    acc.z += __shfl_xor(acc.z, m, 64);
    acc.w += __shfl_xor(acc.w, m, 64);
  }

  if (CLS == 0) {
    if (sub == 0 && node < N) {
      float dn = dinv[node];
      float4 bb = ((const float4*)bias)[fl];
      float4 r;
      r.x = fmaxf(fmaf(acc.x, dn, bb.x), 0.f);
      r.y = fmaxf(fmaf(acc.y, dn, bb.y), 0.f);
      r.z = fmaxf(fmaf(acc.z, dn, bb.z), 0.f);
      r.w = fmaxf(fmaf(acc.w, dn, bb.w), 0.f);
      ((float4*)H)[(size_t)node * 16 + fl] = r;
    }
  } else {
    float a[6] = {0.f, 0.f, 0.f, 0.f, 0.f, 0.f};
    if (sub == 0 && node < N) {
      float dn = dinv[node];
      float4 bb = ((const float4*)bias)[fl];
      float4 r;
      r.x = fmaxf(fmaf(acc.x, dn, bb.x), 0.f);
      r.y = fmaxf(fmaf(acc.y, dn, bb.y), 0.f);
      r.z = fmaxf(fmaf(acc.z, dn, bb.z), 0.f);
      r.w = fmaxf(fmaf(acc.w, dn, bb.w), 0.f);
      // Wc slice for feats 4fl..4fl+3 of this node: 24 contiguous floats
      const float4* w4 = (const float4*)(Wc + (size_t)node * 384 + fl * 24);
      float4 w0 = w4[0], w1 = w4[1], w2 = w4[2], w3 = w4[3], w4_ = w4[4], w5 = w4[5];
      // layout: [f0c0..f0c5 f1c0..f1c5 f2c0..f2c5 f3c0..f3c5]
      a[0] = fmaf(r.x, w0.x, fmaf(r.y, w1.z, fmaf(r.z, w3.x, r.w * w4_.z)));
      a[1] = fmaf(r.x, w0.y, fmaf(r.y, w1.w, fmaf(r.z, w3.y, r.w * w4_.w)));
      a[2] = fmaf(r.x, w0.z, fmaf(r.y, w2.x, fmaf(r.z, w3.z, r.w * w5.x)));
      a[3] = fmaf(r.x, w0.w, fmaf(r.y, w2.y, fmaf(r.z, w3.w, r.w * w5.y)));
      a[4] = fmaf(r.x, w1.x, fmaf(r.y, w2.z, fmaf(r.z, w4_.x, r.w * w5.z)));
      a[5] = fmaf(r.x, w1.y, fmaf(r.y, w2.w, fmaf(r.z, w4_.y, r.w * w5.w)));
    }
#pragma unroll
    for (int c = 0; c < 6; ++c) {
      for (int d = 32; d > 0; d >>= 1) a[c] += __shfl_down(a[c], d, 64);
    }
    __shared__ float sh[4][6];
    if (lane == 0) {
#pragma unroll
      for (int c = 0; c < 6; ++c) sh[wv][c] = a[c];
    }
    __syncthreads();
    if (threadIdx.x == 0) {
#pragma unroll
      for (int c = 0; c < 6; ++c)
        part[(size_t)blockIdx.x * 6 + c] = sh[0][c] + sh[1][c] + sh[2][c] + sh[3][c];
    }
  }
}

// single block: sum part[nb][6], add bias, softmax, write out[6]
__global__ __launch_bounds__(1024) void reduce_softmax(
    const float* __restrict__ part, int nb,
    const float* __restrict__ bc, float* __restrict__ out) {
  int tid = threadIdx.x, lane = tid & 63, wv = tid >> 6;
  float a[6] = {0.f, 0.f, 0.f, 0.f, 0.f, 0.f};
  for (int b = tid; b < nb; b += 1024) {
    const float* p = part + (size_t)b * 6;
#pragma unroll
    for (int c = 0; c < 6; ++c) a[c] += p[c];
  }
#pragma unroll
  for (int c = 0; c < 6; ++c) {
    for (int d = 32; d > 0; d >>= 1) a[c] += __shfl_down(a[c], d, 64);
  }
  __shared__ float sh[16][6];
  if (lane == 0) {
#pragma unroll
    for (int c = 0; c < 6; ++c) sh[wv][c] = a[c];
  }
  __syncthreads();
  if (tid == 0) {
    float l[6], m = -1e30f;
#pragma unroll
    for (int c = 0; c < 6; ++c) {
      float t = 0.f;
      for (int w = 0; w < 16; ++w) t += sh[w][c];
      l[c] = t + bc[c];
      m = fmaxf(m, l[c]);
    }
    float s = 0.f;
#pragma unroll
    for (int c = 0; c < 6; ++c) { l[c] = __expf(l[c] - m); s += l[c]; }
    float inv = 1.f / s;
#pragma unroll
    for (int c = 0; c < 6; ++c) out[c] = l[c] * inv;
  }
}

// ---------------- launch ----------------

static inline size_t align4up(size_t x) { return (x + 3) & ~(size_t)3; }  // 4-elem = 16B

extern "C" void kernel_launch(void* const* d_in, const int* in_sizes, int n_in,
                              void* d_out, int out_size, void* d_ws, size_t ws_size,
                              hipStream_t stream) {
  const float* x  = (const float*)d_in[0];
  const int*   ei = (const int*)d_in[1];
  const float* W1 = (const float*)d_in[2];
  const float* b1 = (const float*)d_in[3];
  const float* W2 = (const float*)d_in[4];
  const float* b2 = (const float*)d_in[5];
  const float* Wc = (const float*)d_in[6];
  const float* bc = (const float*)d_in[7];
  float* out = (float*)d_out;

  const int N = in_sizes[0] / 128;  // 50000
  const int E = in_sizes[1] / 2;    // 800000
  const int* esrc = ei;
  const int* edst = ei + E;
  const int NR = (N + 1023) >> RBITS;  // 49 ranges (<= NR_MAX)
  const int AGRID = (N + 3) / 4;       // aggregate blocks (N%4==0 -> exact)

  // 16B-aligned workspace carve
  size_t o = 0;
  int* offs   = (int*)d_ws + o;           o = align4up(o + N + 1);
  int* srt    = (int*)d_ws + o;           o = align4up(o + E);
  float* dinv = (float*)d_ws + o;         o = align4up(o + N);
  int* ghist  = (int*)d_ws + o;           o = align4up(o + (size_t)NR * NCH);
  ushort* Gb  = (ushort*)((int*)d_ws + o); o = align4up(o + (size_t)N * 32);  // N*64 bf16
  float* bufB = (float*)d_ws + o;         o = align4up(o + (size_t)N * 64);
  float* part = (float*)d_ws + o;         o = align4up(o + (size_t)AGRID * 6);
  int2* ebuf  = (int2*)bufB;  // aliases bufB: dead after csr_range, bufB written by agg1

  hist_ranges<<<NCH, 256, 0, stream>>>(edst, ghist, NR, E);
  scan_ghist<<<1, 1024, 0, stream>>>(ghist, NR * NCH);
  scatter_ranges<<<NCH, 256, 0, stream>>>(esrc, edst, ghist, ebuf, NR, E);
  csr_range<<<NR, 1024, 0, stream>>>(ebuf, ghist, offs, srt, dinv, N, E, NR);

  gemm_scale<128, 32><<<(N + 31) / 32, 256, 0, stream>>>(x, W1, dinv, Gb, N);
  aggregate<0><<<AGRID, 256, 0, stream>>>(Gb, offs, srt, dinv, b1, nullptr, bufB, nullptr, N);
  gemm_scale<64, 32><<<(N + 31) / 32, 256, 0, stream>>>(bufB, W2, dinv, Gb, N);
  aggregate<1><<<AGRID, 256, 0, stream>>>(Gb, offs, srt, dinv, b2, Wc, nullptr, part, N);

  reduce_softmax<<<1, 1024, 0, stream>>>(part, AGRID, bc, out);
}